// Round 5
// baseline (1621.862 us; speedup 1.0000x reference)
//
#include <hip/hip_runtime.h>

// RSNEncoder R5: hoist x-dependent GEMMs off the serial chain.
//   GX[s] = x_s @ Wih^T + bih  (bf16, all 8 s, one launch)
//   MX[j] = x_{2j} @ w2^T      (bf16, 4 slices, one launch)
// Serial chain per step: gh3 = h @ Whh^T (K=512) + gate epilogue reading GX;
// odd steps: mhq = h @ w1^T (K=512) + MX add. Step 0 is elementwise (h=0).
// gh3/gx3: BM=128, 40KBx2 LDS -> 2 blocks/CU (epilogue overlaps other block's
// K-loop). R4 lesson: no exact-fit persistent grids.

#define BDIM 32768
#define DDIM 512
#define BD (BDIM * DDIM)

typedef short bf16x8 __attribute__((ext_vector_type(8)));
typedef float f32x4 __attribute__((ext_vector_type(4)));
typedef unsigned short u16x8 __attribute__((ext_vector_type(8)));

#define AS1 __attribute__((address_space(1)))
#define AS3 __attribute__((address_space(3)))

__device__ __forceinline__ unsigned short f2bf(float f) {
  union { float f; unsigned u; } v; v.f = f;
  return (unsigned short)((v.u + 0x7fffu + ((v.u >> 16) & 1u)) >> 16);  // RNE
}
__device__ __forceinline__ float bf2f(unsigned short b) {
  union { unsigned u; float f; } v; v.u = (unsigned)b << 16; return v.f;
}
__device__ __forceinline__ float sigmf(float x) { return 1.0f / (1.0f + __expf(-x)); }
__device__ __forceinline__ float tanhf_(float x) { return 1.0f - 2.0f / (__expf(2.0f * x) + 1.0f); }
__device__ __forceinline__ void bar() { asm volatile("s_barrier" ::: "memory"); }
#define VMCNT(n) asm volatile("s_waitcnt vmcnt(" #n ")" ::: "memory")

// ---- fp32 -> bf16 (all of x) ----
__global__ void cvt_bf16_all(const float* __restrict__ in, unsigned short* __restrict__ out) {
  const size_t stride = (size_t)gridDim.x * 256;
  for (size_t i = (size_t)blockIdx.x * 256 + threadIdx.x; i < (size_t)BD; i += stride) {
    const size_t o = i * 8;
    const float4 a = *(const float4*)(in + o);
    const float4 b = *(const float4*)(in + o + 4);
    u16x8 v;
    v[0] = f2bf(a.x); v[1] = f2bf(a.y); v[2] = f2bf(a.z); v[3] = f2bf(a.w);
    v[4] = f2bf(b.x); v[5] = f2bf(b.y); v[6] = f2bf(b.z); v[7] = f2bf(b.w);
    *(u16x8*)(out + o) = v;
  }
}

// ---- weight prep: Wg[1536][1024] = [Wih | Whh]; Wm[512][1024] = [w1 | w2] ----
__global__ void prep_w(const float* __restrict__ wih, const float* __restrict__ whh,
                       const float* __restrict__ w1, const float* __restrict__ w2,
                       unsigned short* __restrict__ Wg, unsigned short* __restrict__ Wm) {
  int i = blockIdx.x * 256 + threadIdx.x;
  if (i < 1536 * 1024) {
    const int j = i >> 10, k = i & 1023;
    Wg[i] = f2bf((k < 512) ? wih[j * 512 + k] : whh[j * 512 + (k - 512)]);
  } else {
    i -= 1536 * 1024;
    const int j = i >> 10, k = i & 1023;
    Wm[i] = f2bf((k < 512) ? w1[j * 512 + k] : w2[j * 512 + (k - 512)]);
  }
}

template <int SET>
__device__ __forceinline__ void mfma16(f32x4 (&acc)[3][4][2], const bf16x8 (&av)[4][2],
                                       const bf16x8 (&bv)[2][2]) {
  __builtin_amdgcn_s_setprio(1);
#pragma unroll
  for (int fm = 0; fm < 4; ++fm)
#pragma unroll
    for (int fn = 0; fn < 2; ++fn)
#pragma unroll
      for (int ks = 0; ks < 2; ++ks)
        acc[SET][fm][fn] = __builtin_amdgcn_mfma_f32_16x16x32_bf16(
            av[fm][ks], bv[fn][ks], acc[SET][fm][fn], 0, 0, 0);
  __builtin_amdgcn_s_setprio(0);
}

// ================= 3-gate K=512 GEMM (BM=128, 4 waves, 2 blocks/CU) =================
// MODE 0 (GX): A = xall (s = blockIdx>>11), B = Wih half; out: GX[s] = acc + bih (bf16)
// MODE 1 (GH): A = h_old, B = Whh half; epilogue: gates with GX slice + bhh + h_old
template <int MODE>
__global__ __launch_bounds__(256, 2) void gru3(
    const unsigned short* __restrict__ A, const unsigned short* __restrict__ Wg,
    const float* __restrict__ bih, const float* __restrict__ bhh,
    const unsigned short* __restrict__ GX, unsigned short* __restrict__ out) {
  __shared__ char smem[81920];  // 2 x (A 16K + 3 x B 8K)
  const int t = threadIdx.x;
  const int lane = t & 63, wid = t >> 6;
  const int wm = wid >> 1, wn = wid & 1;  // wave tile 64 rows x 32 gate-cols

  int bidx = blockIdx.x;
  int s = 0;
  if constexpr (MODE == 0) { s = bidx >> 11; bidx &= 2047; }
  const int xcd = bidx & 7, ixc = bidx >> 3;
  const int bm = xcd * 32 + (ixc >> 3);  // [0,256) 128-row blocks
  const int bn = ixc & 7;                // [0,8) 64-col d-blocks
  constexpr int KOFF = (MODE == 0) ? 0 : 8;

  f32x4 acc[3][4][2];
  const f32x4 z4 = {0.f, 0.f, 0.f, 0.f};
#pragma unroll
  for (int g = 0; g < 3; ++g)
#pragma unroll
    for (int a = 0; a < 4; ++a)
#pragma unroll
      for (int b = 0; b < 2; ++b) acc[g][a][b] = z4;

  const int trow = t >> 3;
  const int tcs = (t & 7) * 16;
  int asrc[4], bsrc[3][2];
#pragma unroll
  for (int i = 0; i < 4; ++i) {
    const int r = i * 32 + trow;
    asrc[i] = (bm * 128 + r) * 1024 + (tcs ^ ((r & 7) << 4));
  }
#pragma unroll
  for (int g = 0; g < 3; ++g)
#pragma unroll
    for (int j = 0; j < 2; ++j) {
      const int r = j * 32 + trow;
      bsrc[g][j] = (g * 512 + bn * 64 + r) * 2048 + (tcs ^ ((r & 7) << 4));
    }

  const char* Ac = (const char*)A + (MODE == 0 ? (size_t)s * BD * 2 : 0);
  const char* Wc = (const char*)Wg + KOFF * 128;

  auto issA = [&](int kt, int i) {
    __builtin_amdgcn_global_load_lds((const AS1 void*)(Ac + kt * 128 + asrc[i]),
                                     (AS3 void*)(smem + (kt & 1) * 40960 + i * 4096 + t * 16),
                                     16, 0, 0);
  };
  auto issB = [&](int kt, int g, int j) {
    __builtin_amdgcn_global_load_lds(
        (const AS1 void*)(Wc + kt * 128 + bsrc[g][j]),
        (AS3 void*)(smem + (kt & 1) * 40960 + 16384 + g * 8192 + j * 4096 + t * 16), 16, 0, 0);
  };

  bf16x8 av[4][2], bv[2][2];
  auto readA = [&](const char* pa) {
#pragma unroll
    for (int fm = 0; fm < 4; ++fm)
#pragma unroll
      for (int ks = 0; ks < 2; ++ks) {
        const int r = wm * 64 + fm * 16 + (lane & 15);
        const int c = ks * 64 + (lane >> 4) * 16;
        av[fm][ks] = *(const bf16x8*)(pa + r * 128 + (c ^ ((r & 7) << 4)));
      }
  };
  auto readB = [&](const char* pb, int g) {
#pragma unroll
    for (int fn = 0; fn < 2; ++fn)
#pragma unroll
      for (int ks = 0; ks < 2; ++ks) {
        const int r = wn * 32 + fn * 16 + (lane & 15);
        const int c = ks * 64 + (lane >> 4) * 16;
        bv[fn][ks] = *(const bf16x8*)(pb + g * 8192 + r * 128 + (c ^ ((r & 7) << 4)));
      }
  };

  // prologue (order: A0..3, B0a,B0b, B1a,B1b, B2a,B2b)
  issA(0, 0); issA(0, 1); issA(0, 2); issA(0, 3);
  issB(0, 0, 0); issB(0, 0, 1); issB(0, 1, 0); issB(0, 1, 1); issB(0, 2, 0); issB(0, 2, 1);
  VMCNT(4);  // A + B0 arrived
  bar();

#pragma unroll
  for (int kt = 0; kt < 8; ++kt) {
    const bool last = (kt == 7);
    const char* pa = smem + (kt & 1) * 40960;
    const char* pb = pa + 16384;
    // phase 0: gate r
    readA(pa);
    readB(pb, 0);
    if (!last) { issA(kt + 1, 0); issA(kt + 1, 1); issA(kt + 1, 2); issA(kt + 1, 3); VMCNT(6); }
    else       { VMCNT(2); }
    bar();
    mfma16<0>(acc, av, bv);
    bar();
    // phase 1: gate z
    readB(pb, 1);
    if (!last) { issB(kt + 1, 0, 0); issB(kt + 1, 0, 1); issB(kt + 1, 1, 0); VMCNT(7); }
    else       { VMCNT(0); }
    bar();
    mfma16<1>(acc, av, bv);
    bar();
    // phase 2: gate n
    readB(pb, 2);
    if (!last) { issB(kt + 1, 1, 1); issB(kt + 1, 2, 0); issB(kt + 1, 2, 1); VMCNT(4); }
    bar();
    mfma16<2>(acc, av, bv);
    bar();
  }

  const int erow = (lane >> 4) * 4, ecol = lane & 15;
  if constexpr (MODE == 0) {
    unsigned short* gout = out + (size_t)s * 3 * (size_t)BD;
#pragma unroll
    for (int fn = 0; fn < 2; ++fn) {
      const int d = bn * 64 + wn * 32 + fn * 16 + ecol;
      const float b0 = bih[d], b1 = bih[512 + d], b2 = bih[1024 + d];
#pragma unroll
      for (int fm = 0; fm < 4; ++fm)
#pragma unroll
        for (int j = 0; j < 4; ++j) {
          const size_t row = (size_t)(bm * 128 + wm * 64 + fm * 16 + erow + j);
          gout[row * 1536 + d]        = f2bf(acc[0][fm][fn][j] + b0);
          gout[row * 1536 + 512 + d]  = f2bf(acc[1][fm][fn][j] + b1);
          gout[row * 1536 + 1024 + d] = f2bf(acc[2][fm][fn][j] + b2);
        }
    }
  } else {
#pragma unroll
    for (int fn = 0; fn < 2; ++fn) {
      const int d = bn * 64 + wn * 32 + fn * 16 + ecol;
      const float bhr = bhh[d], bhz = bhh[512 + d], bhn = bhh[1024 + d];
#pragma unroll
      for (int fm = 0; fm < 4; ++fm)
#pragma unroll
        for (int j = 0; j < 4; ++j) {
          const size_t row = (size_t)(bm * 128 + wm * 64 + fm * 16 + erow + j);
          const size_t off = row * 512 + d;
          const float rv = sigmf(bf2f(GX[row * 1536 + d]) + acc[0][fm][fn][j] + bhr);
          const float zv = sigmf(bf2f(GX[row * 1536 + 512 + d]) + acc[1][fm][fn][j] + bhz);
          const float nv = tanhf_(bf2f(GX[row * 1536 + 1024 + d]) +
                                  rv * (acc[2][fm][fn][j] + bhn));
          out[off] = f2bf((1.0f - zv) * nv + zv * bf2f(A[off]));
        }
    }
  }
}

// ================= step 0 (h=0): elementwise from GX[0] =================
__global__ void step0(const unsigned short* __restrict__ GX0, const float* __restrict__ bhh,
                      unsigned short* __restrict__ h1) {
  const int idx = blockIdx.x * 256 + threadIdx.x;
  const size_t row = idx >> 6;
  const int d0 = (idx & 63) * 8;
  const u16x8 gr = *(const u16x8*)&GX0[row * 1536 + d0];
  const u16x8 gz = *(const u16x8*)&GX0[row * 1536 + 512 + d0];
  const u16x8 gn = *(const u16x8*)&GX0[row * 1536 + 1024 + d0];
  u16x8 o;
#pragma unroll
  for (int e = 0; e < 8; ++e) {
    const int d = d0 + e;
    const float rv = sigmf(bf2f(gr[e]) + bhh[d]);
    const float zv = sigmf(bf2f(gz[e]) + bhh[512 + d]);
    const float nv = tanhf_(bf2f(gn[e]) + rv * bhh[1024 + d]);
    o[e] = f2bf((1.0f - zv) * nv);
  }
  *(u16x8*)&h1[row * 512 + d0] = o;
}

// ================= mixed-family 256x256 GEMM, K=512 =================
// MODE 0 (MX): A = x_{2j} (s'=blockIdx>>8), B = w2 half; out bf16 MX[s']
// MODE 1 (MH): A = h, B = w1 half; out bf16 = acc + MX
// MODE 2 (MHF): as 1 but f32 out (final)
template <int MH_, int NH_>
__device__ __forceinline__ void mfmaQ(f32x4 (&acc)[8][4], const bf16x8 (&af)[4][2],
                                      const bf16x8 (&bv)[2][2]) {
  __builtin_amdgcn_s_setprio(1);
#pragma unroll
  for (int fm = 0; fm < 4; ++fm)
#pragma unroll
    for (int fn = 0; fn < 2; ++fn)
#pragma unroll
      for (int ks = 0; ks < 2; ++ks)
        acc[MH_ * 4 + fm][NH_ * 2 + fn] = __builtin_amdgcn_mfma_f32_16x16x32_bf16(
            af[fm][ks], bv[fn][ks], acc[MH_ * 4 + fm][NH_ * 2 + fn], 0, 0, 0);
  __builtin_amdgcn_s_setprio(0);
}

template <int MODE>
__global__ __launch_bounds__(512, 2) void mixq(
    const unsigned short* __restrict__ A, const unsigned short* __restrict__ Wm,
    const unsigned short* __restrict__ MXin,
    unsigned short* __restrict__ outB, float* __restrict__ outF) {
  __shared__ char smem[131072];
  const int t = threadIdx.x;
  const int lane = t & 63, wid = t >> 6;
  const int wm = wid >> 2, wn = wid & 3;
  int bidx = blockIdx.x;
  int s2 = 0;
  if constexpr (MODE == 0) { s2 = bidx >> 8; bidx &= 255; }
  const int xcd = bidx & 7, ixc = bidx >> 3;
  const int bm = xcd * 16 + (ixc >> 1);
  const int bn = ixc & 1;
  constexpr int KOFF = (MODE == 0) ? 8 : 0;

  f32x4 acc[8][4];
  const f32x4 z4 = {0.f, 0.f, 0.f, 0.f};
#pragma unroll
  for (int a = 0; a < 8; ++a)
#pragma unroll
    for (int b = 0; b < 4; ++b) acc[a][b] = z4;

  const int trow = t >> 3;
  const int tcs = (t & 7) * 16;
  int asrc[4], bsrc[4];
#pragma unroll
  for (int i = 0; i < 4; ++i) {
    const int r = i * 64 + trow;
    asrc[i] = (bm * 256 + r) * 1024 + (tcs ^ ((r & 7) << 4));
    bsrc[i] = (bn * 256 + r) * 2048 + (tcs ^ ((r & 7) << 4));
  }
  const char* Ac = (const char*)A + (MODE == 0 ? (size_t)s2 * 2 * (size_t)BD * 2 : 0);
  const char* Wc = (const char*)Wm + KOFF * 128;

  auto issA = [&](int kt, int i) {
    __builtin_amdgcn_global_load_lds((const AS1 void*)(Ac + kt * 128 + asrc[i]),
                                     (AS3 void*)(smem + (kt & 1) * 65536 + i * 8192 + t * 16),
                                     16, 0, 0);
  };
  auto issB = [&](int kt, int i) {
    __builtin_amdgcn_global_load_lds(
        (const AS1 void*)(Wc + kt * 128 + bsrc[i]),
        (AS3 void*)(smem + (kt & 1) * 65536 + 32768 + i * 8192 + t * 16), 16, 0, 0);
  };

  bf16x8 af[4][2], bf0[2][2], bf1[2][2];
  auto readAm = [&](const char* pa, int mh) {
#pragma unroll
    for (int fm = 0; fm < 4; ++fm)
#pragma unroll
      for (int ks = 0; ks < 2; ++ks) {
        const int r = mh * 128 + wm * 64 + fm * 16 + (lane & 15);
        const int c = ks * 64 + (lane >> 4) * 16;
        af[fm][ks] = *(const bf16x8*)(pa + r * 128 + (c ^ ((r & 7) << 4)));
      }
  };
  auto readBm = [&](const char* pb, int nh, bf16x8 (&bv)[2][2]) {
#pragma unroll
    for (int fn = 0; fn < 2; ++fn)
#pragma unroll
      for (int ks = 0; ks < 2; ++ks) {
        const int r = nh * 128 + wn * 32 + fn * 16 + (lane & 15);
        const int c = ks * 64 + (lane >> 4) * 16;
        bv[fn][ks] = *(const bf16x8*)(pb + r * 128 + (c ^ ((r & 7) << 4)));
      }
  };

  issA(0, 0); issA(0, 1); issB(0, 0); issB(0, 1);
  issB(0, 2); issB(0, 3); issA(0, 2); issA(0, 3);
  VMCNT(4);
  bar();

#pragma unroll
  for (int kt = 0; kt < 8; ++kt) {
    const bool last = (kt == 7);
    const char* pa = smem + (kt & 1) * 65536;
    const char* pb = pa + 32768;
    readAm(pa, 0);
    readBm(pb, 0, bf0);
    if (!last) { issA(kt + 1, 0); issA(kt + 1, 1); VMCNT(4); }
    else       { VMCNT(2); }
    bar();
    mfmaQ<0, 0>(acc, af, bf0);
    bar();
    readBm(pb, 1, bf1);
    if (!last) { issB(kt + 1, 0); issB(kt + 1, 1); VMCNT(4); }
    else       { VMCNT(0); }
    bar();
    mfmaQ<0, 1>(acc, af, bf1);
    bar();
    readAm(pa, 1);
    if (!last) { issB(kt + 1, 2); issB(kt + 1, 3); }
    bar();
    mfmaQ<1, 0>(acc, af, bf0);
    bar();
    if (!last) { issA(kt + 1, 2); issA(kt + 1, 3); VMCNT(4); }
    bar();
    mfmaQ<1, 1>(acc, af, bf1);
    bar();
  }

  const int erow = (lane >> 4) * 4, ecol = lane & 15;
  unsigned short* oB = (MODE == 0) ? outB + (size_t)s2 * (size_t)BD : outB;
#pragma unroll
  for (int mh = 0; mh < 2; ++mh)
#pragma unroll
    for (int fm = 0; fm < 4; ++fm)
#pragma unroll
      for (int nh = 0; nh < 2; ++nh)
#pragma unroll
        for (int fn = 0; fn < 2; ++fn) {
          const int col = bn * 256 + nh * 128 + wn * 32 + fn * 16 + ecol;
#pragma unroll
          for (int j = 0; j < 4; ++j) {
            const size_t row = (size_t)(bm * 256 + mh * 128 + wm * 64 + fm * 16 + erow + j);
            const size_t off = row * 512 + col;
            float v = acc[mh * 4 + fm][nh * 2 + fn][j];
            if constexpr (MODE != 0) v += bf2f(MXin[off]);
            if constexpr (MODE == 2) outF[off] = v;
            else                     oB[off] = f2bf(v);
          }
        }
}

extern "C" void kernel_launch(void* const* d_in, const int* in_sizes, int n_in,
                              void* d_out, int out_size, void* d_ws, size_t ws_size,
                              hipStream_t stream) {
  const float* x   = (const float*)d_in[0];
  const float* wih = (const float*)d_in[1];
  const float* whh = (const float*)d_in[2];
  const float* bih = (const float*)d_in[3];
  const float* bhh = (const float*)d_in[4];
  const float* w1  = (const float*)d_in[5];
  const float* w2  = (const float*)d_in[6];

  char* ws = (char*)d_ws;
  const size_t bd2 = (size_t)BD * 2;                               // 32 MB
  unsigned short* xall  = (unsigned short*)ws;                     // 8 slices
  unsigned short* hb[2] = {(unsigned short*)(ws + 8 * bd2),
                           (unsigned short*)(ws + 9 * bd2)};
  unsigned short* MX    = (unsigned short*)(ws + 10 * bd2);        // 4 slices
  unsigned short* GXb   = (unsigned short*)(ws + 14 * bd2);        // 8 x 3*BD elems
  unsigned short* Wg    = (unsigned short*)(ws + 38 * bd2);        // 3 MB
  unsigned short* Wm    = Wg + 1536 * 1024;                        // 1 MB

  cvt_bf16_all<<<2048, 256, 0, stream>>>(x, xall);
  prep_w<<<8192, 256, 0, stream>>>(wih, whh, w1, w2, Wg, Wm);

  // parallel precompute
  gru3<0><<<16384, 256, 0, stream>>>(xall, Wg, bih, bhh, nullptr, GXb);
  mixq<0><<<1024, 512, 0, stream>>>(xall, Wm, nullptr, MX, nullptr);

  // step 0 (h = 0)
  step0<<<8192, 256, 0, stream>>>(GXb, bhh, hb[0]);

  int hp = 0;
  for (int i = 1; i < 8; ++i) {
    const unsigned short* GXi = GXb + (size_t)i * 3 * (size_t)BD;
    gru3<1><<<2048, 256, 0, stream>>>(hb[hp], Wg, bih, bhh, GXi, hb[hp ^ 1]);
    hp ^= 1;
    if (i & 1) {
      const unsigned short* mx = MX + (size_t)((i - 1) / 2) * (size_t)BD;
      if (i == 7) {
        mixq<2><<<256, 512, 0, stream>>>(hb[hp], Wm, mx, nullptr, (float*)d_out);
      } else {
        mixq<1><<<256, 512, 0, stream>>>(hb[hp], Wm, mx, hb[hp ^ 1], nullptr);
        hp ^= 1;
      }
    }
  }
}

// Round 6
// 1229.219 us; speedup vs baseline: 1.3194x; 1.3194x over previous
//
#include <hip/hip_runtime.h>

// RSNEncoder R6: R3 launch structure; gates kernel rebuilt:
//  - wave = 64 rows x 96 gate-cols (2 frags/gate interleaved) -> 2 balanced
//    ks-phases per K-tile {10 ds_read_b128, 24 MFMA}, 4 barriers/tile.
//  - A triple-buffered (2-tile lookahead, HBM latency), B double-buffered
//    (L2-hot weights). vmcnt(4) steady, vmcnt(0) only at drain.
// Mixed GEMM = R3 verbatim. T1 XCD swizzle, T2 LDS swizzle, T5 setprio.

#define BDIM 32768
#define DDIM 512
#define BD (BDIM * DDIM)

typedef short bf16x8 __attribute__((ext_vector_type(8)));
typedef float f32x4 __attribute__((ext_vector_type(4)));
typedef unsigned short u16x8 __attribute__((ext_vector_type(8)));

#define AS1 __attribute__((address_space(1)))
#define AS3 __attribute__((address_space(3)))

__device__ __forceinline__ unsigned short f2bf(float f) {
  union { float f; unsigned u; } v; v.f = f;
  return (unsigned short)((v.u + 0x7fffu + ((v.u >> 16) & 1u)) >> 16);  // RNE
}
__device__ __forceinline__ float bf2f(unsigned short b) {
  union { unsigned u; float f; } v; v.u = (unsigned)b << 16; return v.f;
}
__device__ __forceinline__ float sigmf(float x) { return 1.0f / (1.0f + __expf(-x)); }
__device__ __forceinline__ float tanhf_(float x) { return 1.0f - 2.0f / (__expf(2.0f * x) + 1.0f); }
__device__ __forceinline__ void bar() { asm volatile("s_barrier" ::: "memory"); }
#define VMCNT(n) asm volatile("s_waitcnt vmcnt(" #n ")" ::: "memory")

// ---- fp32 -> bf16 (all of x) ----
__global__ void cvt_bf16_all(const float* __restrict__ in, unsigned short* __restrict__ out) {
  const size_t stride = (size_t)gridDim.x * 256;
  for (size_t i = (size_t)blockIdx.x * 256 + threadIdx.x; i < (size_t)BD; i += stride) {
    const size_t o = i * 8;
    const float4 a = *(const float4*)(in + o);
    const float4 b = *(const float4*)(in + o + 4);
    u16x8 v;
    v[0] = f2bf(a.x); v[1] = f2bf(a.y); v[2] = f2bf(a.z); v[3] = f2bf(a.w);
    v[4] = f2bf(b.x); v[5] = f2bf(b.y); v[6] = f2bf(b.z); v[7] = f2bf(b.w);
    *(u16x8*)(out + o) = v;
  }
}

// ---- weight prep: Wg[1536][1024] = [Wih | Whh]; Wm[512][1024] = [w1 | w2] ----
__global__ void prep_w(const float* __restrict__ wih, const float* __restrict__ whh,
                       const float* __restrict__ w1, const float* __restrict__ w2,
                       unsigned short* __restrict__ Wg, unsigned short* __restrict__ Wm) {
  int i = blockIdx.x * 256 + threadIdx.x;
  if (i < 1536 * 1024) {
    const int j = i >> 10, k = i & 1023;
    Wg[i] = f2bf((k < 512) ? wih[j * 512 + k] : whh[j * 512 + (k - 512)]);
  } else {
    i -= 1536 * 1024;
    const int j = i >> 10, k = i & 1023;
    Wm[i] = f2bf((k < 512) ? w1[j * 512 + k] : w2[j * 512 + (k - 512)]);
  }
}

// ================= gates kernel =================
// Block: 256 rows x 64 d-cols (192 gate-cols). 8 waves = 4m x 2n; wave tile
// 64 rows x 96 gate-cols (frag fn: gate = fn>>1, col = gate*64+(fn&1)*32+wn*16).
// K = 1024 (kt<8 from X, kt>=8 from H), 16 K-tiles, 2 ks-phases each.
// LDS: A bufs x3 @ 0/32K/64K (32 KB each), B bufs x2 @ 96K/120K (24 KB each).
// acc[fm][ai]: ai 0,1=r  2,3=z  4,5=i_n  6,7=h_n (e = ai&1 col-half).
__global__ __launch_bounds__(512, 2) void gru_gates(
    const unsigned short* __restrict__ X, const unsigned short* __restrict__ H,
    const unsigned short* __restrict__ Wg, const float* __restrict__ bih,
    const float* __restrict__ bhh, unsigned short* __restrict__ outB) {
  __shared__ char smem[147456];
  const int t = threadIdx.x;
  const int lane = t & 63, wid = t >> 6;
  const int wm = wid >> 1, wn = wid & 1;
  const int xcd = blockIdx.x & 7, ixc = blockIdx.x >> 3;
  const int bm = xcd * 16 + (ixc >> 3);  // 128 m-blocks
  const int bn = ixc & 7;                // 8 d-blocks

  f32x4 acc[4][8];
  const f32x4 z4 = {0.f, 0.f, 0.f, 0.f};
#pragma unroll
  for (int a = 0; a < 4; ++a)
#pragma unroll
    for (int b = 0; b < 8; ++b) acc[a][b] = z4;

  // staging source offsets (pre-swizzled col slot; rule #21)
  const int trow = t >> 3;
  const int tswz = ((t & 7) * 16) ^ ((trow & 7) << 4);
  int asrc[4], bsrc[3];
#pragma unroll
  for (int i = 0; i < 4; ++i) asrc[i] = (bm * 256 + i * 64 + trow) * 1024 + tswz;
#pragma unroll
  for (int g = 0; g < 3; ++g) bsrc[g] = (g * 512 + bn * 64 + trow) * 2048 + tswz;

  const char* Xc = (const char*)X;
  const char* Hc = (const char*)H;
  const char* Wc = (const char*)Wg;

  auto issA = [&](int tt, int i) {  // A-tile tt -> buf tt%3 (tt folds: loop unrolled)
    const char* base = ((tt < 8) ? Xc : Hc) + (tt & 7) * 128 + asrc[i];
    __builtin_amdgcn_global_load_lds(
        (const AS1 void*)base,
        (AS3 void*)(smem + (tt % 3) * 32768 + i * 8192 + t * 16), 16, 0, 0);
  };
  auto issB = [&](int tt, int g) {  // B-tile tt -> buf tt&1
    const char* base = Wc + tt * 128 + bsrc[g];
    __builtin_amdgcn_global_load_lds(
        (const AS1 void*)base,
        (AS3 void*)(smem + 98304 + (tt & 1) * 24576 + g * 8192 + t * 16), 16, 0, 0);
  };

  // prologue: A(0), B(0), A(1) in flight; certify A(0)+B(0)
  issA(0, 0); issA(0, 1); issA(0, 2); issA(0, 3);
  issB(0, 0); issB(0, 1); issB(0, 2);
  issA(1, 0); issA(1, 1); issA(1, 2); issA(1, 3);
  VMCNT(4);
  bar();

#pragma unroll
  for (int kt = 0; kt < 16; ++kt) {
    const char* pa = smem + (kt % 3) * 32768;
    const char* pb = smem + 98304 + (kt & 1) * 24576;
#pragma unroll
    for (int ph = 0; ph < 2; ++ph) {
      bf16x8 av[4], bv[6];
      const int ksb = ph * 64 + (lane >> 4) * 16;
#pragma unroll
      for (int fm = 0; fm < 4; ++fm) {
        const int r = wm * 64 + fm * 16 + (lane & 15);
        av[fm] = *(const bf16x8*)(pa + r * 128 + (ksb ^ ((r & 7) << 4)));
      }
#pragma unroll
      for (int fn = 0; fn < 6; ++fn) {
        const int c = (fn >> 1) * 64 + (fn & 1) * 32 + wn * 16 + (lane & 15);
        bv[fn] = *(const bf16x8*)(pb + c * 128 + (ksb ^ ((c & 7) << 4)));
      }
      if (ph == 0) {
        if (kt < 15) { issB(kt + 1, 0); issB(kt + 1, 1); issB(kt + 1, 2); }
        // no vmcnt: ph1 reads the same (certified) tile
      } else {
        if (kt < 14) {
          issA(kt + 2, 0); issA(kt + 2, 1); issA(kt + 2, 2); issA(kt + 2, 3);
          VMCNT(4);  // certify A(kt+1) (1 tile old) + B(kt+1) (2 phases old)
        } else if (kt == 14) {
          VMCNT(0);  // drain: A(15), B(15)
        }
      }
      bar();
      __builtin_amdgcn_s_setprio(1);
#pragma unroll
      for (int fn = 0; fn < 6; ++fn) {
        const int ai = (fn < 4 || kt < 8) ? fn : fn + 2;  // n-frags: i_n vs h_n
#pragma unroll
        for (int fm = 0; fm < 4; ++fm)
          acc[fm][ai] = __builtin_amdgcn_mfma_f32_16x16x32_bf16(av[fm], bv[fn],
                                                               acc[fm][ai], 0, 0, 0);
      }
      __builtin_amdgcn_s_setprio(0);
      bar();
    }
  }

  // epilogue: gate math (C/D map col=lane&15, row=(lane>>4)*4+j)
  const int erow = (lane >> 4) * 4, ecol = lane & 15;
#pragma unroll
  for (int e = 0; e < 2; ++e) {
    const int d = bn * 64 + e * 32 + wn * 16 + ecol;
    const float br = bih[d] + bhh[d];
    const float bz = bih[512 + d] + bhh[512 + d];
    const float bi = bih[1024 + d];
    const float bh = bhh[1024 + d];
#pragma unroll
    for (int fm = 0; fm < 4; ++fm)
#pragma unroll
      for (int j = 0; j < 4; ++j) {
        const int row = bm * 256 + wm * 64 + fm * 16 + erow + j;
        const size_t off = (size_t)row * 512 + d;
        const float rv = sigmf(acc[fm][0 + e][j] + br);
        const float zv = sigmf(acc[fm][2 + e][j] + bz);
        const float nv = tanhf_(acc[fm][4 + e][j] + bi + rv * (acc[fm][6 + e][j] + bh));
        outB[off] = f2bf((1.0f - zv) * nv + zv * bf2f(H[off]));
      }
  }
}

// ================= mixed kernel: out = [h | x_prev] @ [w1|w2]^T (R3 verbatim) =================
template <int MH, int NH>
__device__ __forceinline__ void mfmaQ(f32x4 (&acc)[8][4], const bf16x8 (&af)[4][2],
                                      const bf16x8 (&bv)[2][2]) {
  __builtin_amdgcn_s_setprio(1);
#pragma unroll
  for (int fm = 0; fm < 4; ++fm)
#pragma unroll
    for (int fn = 0; fn < 2; ++fn)
#pragma unroll
      for (int ks = 0; ks < 2; ++ks)
        acc[MH * 4 + fm][NH * 2 + fn] = __builtin_amdgcn_mfma_f32_16x16x32_bf16(
            af[fm][ks], bv[fn][ks], acc[MH * 4 + fm][NH * 2 + fn], 0, 0, 0);
  __builtin_amdgcn_s_setprio(0);
}

template <int WF>
__global__ __launch_bounds__(512, 2) void mixed_gemm(
    const unsigned short* __restrict__ Ka, const unsigned short* __restrict__ Kb,
    const unsigned short* __restrict__ Wm,
    unsigned short* __restrict__ outB, float* __restrict__ outF) {
  __shared__ char smem[131072];
  const int t = threadIdx.x;
  const int lane = t & 63, wid = t >> 6;
  const int wm = wid >> 2, wn = wid & 3;
  const int xcd = blockIdx.x & 7, ixc = blockIdx.x >> 3;
  const int bm = xcd * 16 + (ixc >> 1);
  const int bn = ixc & 1;

  f32x4 acc[8][4];
  const f32x4 z4 = {0.f, 0.f, 0.f, 0.f};
#pragma unroll
  for (int a = 0; a < 8; ++a)
#pragma unroll
    for (int b = 0; b < 4; ++b) acc[a][b] = z4;

  const int trow = t >> 3;
  const int tswz = ((t & 7) * 16) ^ ((trow & 7) << 4);
  int asrc[4], bsrc[4];
#pragma unroll
  for (int i = 0; i < 4; ++i) {
    asrc[i] = (bm * 256 + i * 64 + trow) * 1024 + tswz;
    bsrc[i] = (bn * 256 + i * 64 + trow) * 2048 + tswz;
  }
  const char* Kac = (const char*)Ka;
  const char* Kbc = (const char*)Kb;
  const char* Wc = (const char*)Wm;

  auto issA = [&](int kt, int i) {
    const char* base = ((kt < 8) ? Kac : Kbc) + (kt & 7) * 128 + asrc[i];
    __builtin_amdgcn_global_load_lds(
        (const AS1 void*)base,
        (AS3 void*)(smem + (kt & 1) * 65536 + i * 8192 + t * 16), 16, 0, 0);
  };
  auto issB = [&](int kt, int i) {
    const char* base = Wc + kt * 128 + bsrc[i];
    __builtin_amdgcn_global_load_lds(
        (const AS1 void*)base,
        (AS3 void*)(smem + (kt & 1) * 65536 + 32768 + i * 8192 + t * 16), 16, 0, 0);
  };

  bf16x8 af[4][2], bf0[2][2], bf1[2][2];
  auto readAm = [&](const char* pa, int mh) {
#pragma unroll
    for (int fm = 0; fm < 4; ++fm)
#pragma unroll
      for (int ks = 0; ks < 2; ++ks) {
        const int r = mh * 128 + wm * 64 + fm * 16 + (lane & 15);
        const int c = ks * 64 + (lane >> 4) * 16;
        af[fm][ks] = *(const bf16x8*)(pa + r * 128 + (c ^ ((r & 7) << 4)));
      }
  };
  auto readBm = [&](const char* pb, int nh, bf16x8 (&bv)[2][2]) {
#pragma unroll
    for (int fn = 0; fn < 2; ++fn)
#pragma unroll
      for (int ks = 0; ks < 2; ++ks) {
        const int r = nh * 128 + wn * 32 + fn * 16 + (lane & 15);
        const int c = ks * 64 + (lane >> 4) * 16;
        bv[fn][ks] = *(const bf16x8*)(pb + r * 128 + (c ^ ((r & 7) << 4)));
      }
  };

  issA(0, 0); issA(0, 1); issB(0, 0); issB(0, 1);
  issB(0, 2); issB(0, 3); issA(0, 2); issA(0, 3);
  VMCNT(4);
  bar();

  for (int kt = 0; kt < 16; ++kt) {
    const bool last = (kt == 15);
    const char* pa = smem + (kt & 1) * 65536;
    const char* pb = pa + 32768;
    readAm(pa, 0);
    readBm(pb, 0, bf0);
    if (!last) { issA(kt + 1, 0); issA(kt + 1, 1); VMCNT(4); }
    else       { VMCNT(2); }
    bar();
    mfmaQ<0, 0>(acc, af, bf0);
    bar();
    readBm(pb, 1, bf1);
    if (!last) { issB(kt + 1, 0); issB(kt + 1, 1); VMCNT(4); }
    else       { VMCNT(0); }
    bar();
    mfmaQ<0, 1>(acc, af, bf1);
    bar();
    readAm(pa, 1);
    if (!last) { issB(kt + 1, 2); issB(kt + 1, 3); }
    bar();
    mfmaQ<1, 0>(acc, af, bf0);
    bar();
    if (!last) { issA(kt + 1, 2); issA(kt + 1, 3); VMCNT(4); }
    bar();
    mfmaQ<1, 1>(acc, af, bf1);
    bar();
  }

  const int erow = (lane >> 4) * 4, ecol = lane & 15;
#pragma unroll
  for (int mh = 0; mh < 2; ++mh)
#pragma unroll
    for (int fm = 0; fm < 4; ++fm)
#pragma unroll
      for (int nh = 0; nh < 2; ++nh)
#pragma unroll
        for (int fn = 0; fn < 2; ++fn) {
          const int col = bn * 256 + nh * 128 + wn * 32 + fn * 16 + ecol;
#pragma unroll
          for (int j = 0; j < 4; ++j) {
            const int row = bm * 256 + mh * 128 + wm * 64 + fm * 16 + erow + j;
            const size_t off = (size_t)row * 512 + col;
            const float v = acc[mh * 4 + fm][nh * 2 + fn][j];
            if constexpr (WF) outF[off] = v;
            else              outB[off] = f2bf(v);
          }
        }
}

extern "C" void kernel_launch(void* const* d_in, const int* in_sizes, int n_in,
                              void* d_out, int out_size, void* d_ws, size_t ws_size,
                              hipStream_t stream) {
  const float* x   = (const float*)d_in[0];
  const float* wih = (const float*)d_in[1];
  const float* whh = (const float*)d_in[2];
  const float* bih = (const float*)d_in[3];
  const float* bhh = (const float*)d_in[4];
  const float* w1  = (const float*)d_in[5];
  const float* w2  = (const float*)d_in[6];

  char* ws = (char*)d_ws;
  const size_t bd2 = (size_t)BD * 2;
  unsigned short* xall  = (unsigned short*)ws;                  // 8 x 32 MB
  unsigned short* hb[2] = {(unsigned short*)(ws + 8 * bd2),
                           (unsigned short*)(ws + 9 * bd2)};    // 32 MB each
  unsigned short* Wg = (unsigned short*)(ws + 10 * bd2);        // 3 MB
  unsigned short* Wm = Wg + 1536 * 1024;                        // 1 MB

  hipMemsetAsync(hb[0], 0, bd2, stream);  // h0 = 0
  cvt_bf16_all<<<2048, 256, 0, stream>>>(x, xall);
  prep_w<<<8192, 256, 0, stream>>>(wih, whh, w1, w2, Wg, Wm);

  int hp = 0;
  for (int i = 0; i < 8; ++i) {
    const unsigned short* xi = xall + (size_t)i * BD;
    gru_gates<<<1024, 512, 0, stream>>>(xi, hb[hp], Wg, bih, bhh, hb[hp ^ 1]);
    hp ^= 1;
    if (i & 1) {
      const unsigned short* xprev = xall + (size_t)(i - 1) * BD;
      if (i == 7)
        mixed_gemm<1><<<256, 512, 0, stream>>>(hb[hp], xprev, Wm, nullptr, (float*)d_out);
      else
        mixed_gemm<0><<<256, 512, 0, stream>>>(hb[hp], xprev, Wm, hb[hp ^ 1], nullptr);
      if (i != 7) hp ^= 1;
    }
  }
}